// Round 7
// baseline (286.280 us; speedup 1.0000x reference)
//
#include <hip/hip_runtime.h>

#define N_NODES 32768
#define N_EDGES 16384
#define DEG 4
#define KPE 8
#define DIM 128
#define EDIM 64

typedef float f32x4 __attribute__((ext_vector_type(4)));
typedef __bf16 bf16x8 __attribute__((ext_vector_type(8)));
typedef __bf16 bf16x2 __attribute__((ext_vector_type(2)));
typedef unsigned short u16x8 __attribute__((ext_vector_type(8)));
typedef unsigned int u32;

static __device__ __forceinline__ unsigned short f2bf(float f) {
  union { float f; unsigned int u; } v; v.f = f;
  unsigned int r = (v.u + 0x7FFFu + ((v.u >> 16) & 1u)) >> 16;
  return (unsigned short)r;
}
static __device__ __forceinline__ float bflo(unsigned int v) {
  union { unsigned int u; float f; } x; x.u = v << 16; return x.f;
}
static __device__ __forceinline__ float bfhi(unsigned int v) {
  union { unsigned int u; float f; } x; x.u = v & 0xffff0000u; return x.f;
}

#if __has_builtin(__builtin_amdgcn_fdot2_f32_bf16)
static __device__ __forceinline__ float dot2bf(unsigned int a, unsigned int b, float c) {
  return __builtin_amdgcn_fdot2_f32_bf16(
      __builtin_bit_cast(bf16x2, a), __builtin_bit_cast(bf16x2, b), c, false);
}
#else
static __device__ __forceinline__ float dot2bf(unsigned int a, unsigned int b, float c) {
  c = fmaf(bflo(a), bflo(b), c);
  return fmaf(bfhi(a), bfhi(b), c);
}
#endif

// ---------------- weight combine ----------------
__global__ __launch_bounds__(256) void wprep_kernel(
    const float* __restrict__ Wq, const float* __restrict__ Wk,
    const float* __restrict__ Wv, const float* __restrict__ Wlin,
    const float* __restrict__ Wedge, const float* __restrict__ Wo,
    unsigned short* __restrict__ CW, unsigned short* __restrict__ CWE,
    unsigned short* __restrict__ Wob)
{
  int id = blockIdx.x * 256 + threadIdx.x;
  if (id < 384 * 128) {
    int j = id >> 7, i = id & 127;
    const float* wrow; float scale = 1.0f;
    if (j < 128)      { wrow = Wq + j * 128; scale = 0.25f; }
    else if (j < 256) { wrow = Wk + (j - 128) * 128; }
    else              { wrow = Wv + (j - 256) * 128; }
    float s = 0.f;
    #pragma unroll 8
    for (int m = 0; m < 128; ++m) s += wrow[m] * Wlin[m * 128 + i];
    CW[id] = f2bf(s * scale);
  } else if (id < 384 * 128 + 128 * 64) {
    int id2 = id - 384 * 128; int j = id2 >> 6, t = id2 & 63;
    float s = 0.f;
    #pragma unroll 8
    for (int m = 0; m < 128; ++m) s += Wk[j * 128 + m] * Wedge[m * 64 + t];
    CWE[id2] = f2bf(s);
  } else if (id < 384 * 128 + 128 * 64 + 128 * 128) {
    int id3 = id - (384 * 128 + 128 * 64);
    Wob[id3] = f2bf(Wo[id3]);
  }
}

// ---------------- G12: fused g1 + g2 -----------
__global__ __launch_bounds__(256) void g12_kernel(
    const float* __restrict__ x, const unsigned short* __restrict__ CW,
    const float* __restrict__ bq, const float* __restrict__ bv,
    unsigned short* __restrict__ qb, unsigned short* __restrict__ Kb,
    unsigned short* __restrict__ Vb,
    const float* __restrict__ ea, const unsigned short* __restrict__ CWE,
    const float* __restrict__ bk, unsigned short* __restrict__ WeKb)
{
  const int wave = threadIdx.x >> 6, lane = threadIdx.x & 63;
  const int r16 = lane & 15, quad = lane >> 4;

  if (blockIdx.x < 512) {
    const int m0 = blockIdx.x * 64 + wave * 16;
    u16x8 av[4];
    const float* arow = x + (size_t)(m0 + r16) * DIM + quad * 8;
    #pragma unroll
    for (int kk = 0; kk < 4; ++kk) {
      float4 a0 = *(const float4*)(arow + kk * 32);
      float4 a1 = *(const float4*)(arow + kk * 32 + 4);
      u16x8 au;
      au[0] = f2bf(a0.x); au[1] = f2bf(a0.y); au[2] = f2bf(a0.z); au[3] = f2bf(a0.w);
      au[4] = f2bf(a1.x); au[5] = f2bf(a1.y); au[6] = f2bf(a1.z); au[7] = f2bf(a1.w);
      av[kk] = au;
    }
    #pragma unroll
    for (int g = 0; g < 6; ++g) {
      f32x4 acc[4];
      const f32x4 z = {0.f, 0.f, 0.f, 0.f};
      acc[0] = z; acc[1] = z; acc[2] = z; acc[3] = z;
      #pragma unroll
      for (int kk = 0; kk < 4; ++kk) {
        #pragma unroll
        for (int s = 0; s < 4; ++s) {
          u16x8 bu = *(const u16x8*)(CW + (size_t)(g * 64 + s * 16 + r16) * DIM + kk * 32 + quad * 8);
          acc[s] = __builtin_amdgcn_mfma_f32_16x16x32_bf16(
              __builtin_bit_cast(bf16x8, av[kk]), __builtin_bit_cast(bf16x8, bu), acc[s], 0, 0, 0);
        }
      }
      const int arr = g >> 1;
      const int colbase = (g & 1) * 64;
      unsigned short* dst = arr == 0 ? qb : (arr == 1 ? Kb : Vb);
      #pragma unroll
      for (int s = 0; s < 4; ++s) {
        int j = colbase + s * 16 + r16;
        float bias = arr == 0 ? 0.25f * bq[j] : (arr == 2 ? bv[j] : 0.f);
        #pragma unroll
        for (int r = 0; r < 4; ++r) {
          int m = m0 + quad * 4 + r;
          dst[(size_t)m * DIM + j] = f2bf(acc[s][r] + bias);
        }
      }
    }
  } else {
    const int idx = blockIdx.x - 512;
    const int m0 = (idx >> 1) * 64 + wave * 16;
    const int n0 = (idx & 1) * 64;
    f32x4 acc[4];
    const f32x4 z = {0.f, 0.f, 0.f, 0.f};
    acc[0] = z; acc[1] = z; acc[2] = z; acc[3] = z;
    const float* arow = ea + (size_t)(m0 + r16) * EDIM + quad * 8;
    #pragma unroll
    for (int kk = 0; kk < 2; ++kk) {
      float4 a0 = *(const float4*)(arow + kk * 32);
      float4 a1 = *(const float4*)(arow + kk * 32 + 4);
      u16x8 au;
      au[0] = f2bf(a0.x); au[1] = f2bf(a0.y); au[2] = f2bf(a0.z); au[3] = f2bf(a0.w);
      au[4] = f2bf(a1.x); au[5] = f2bf(a1.y); au[6] = f2bf(a1.z); au[7] = f2bf(a1.w);
      bf16x8 av = __builtin_bit_cast(bf16x8, au);
      #pragma unroll
      for (int s = 0; s < 4; ++s) {
        u16x8 bu = *(const u16x8*)(CWE + (size_t)(n0 + s * 16 + r16) * EDIM + kk * 32 + quad * 8);
        acc[s] = __builtin_amdgcn_mfma_f32_16x16x32_bf16(
            av, __builtin_bit_cast(bf16x8, bu), acc[s], 0, 0, 0);
      }
    }
    #pragma unroll
    for (int s = 0; s < 4; ++s) {
      int j = n0 + s * 16 + r16;
      float bias = bk[j];
      #pragma unroll
      for (int r = 0; r < 4; ++r) {
        int m = m0 + quad * 4 + r;
        WeKb[(size_t)m * DIM + j] = f2bf(acc[s][r] + bias);
      }
    }
  }
}

// ---------------- G3: attention, node-level software pipeline ----------------
// 1 block = 1 wave = 8 nodes. Double-buffered LDS; ALL operands staged by DMA
// (45 VMEM ops/node: 32 K width-4 + 4 E + 1 q + 8 V width-16=4rows/instr).
// While computing node k, node k+1's batch is in flight. In-order vmcnt (m135)
// gives exact fences: vmcnt(54) = K/E/q of node k ready (V+store+next-stage
// younger), vmcnt(46) = all of node k ready. Constants assume index loads
// scalarize to SMEM (lgkmcnt); if they stay VMEM we merely over-wait by 9.
#define OFF_V 0
#define OFF_K 8192
#define OFF_E 16896
#define OFF_Q 17984
#define BUFSZ 18256
#define OFF_P 36512

struct IdxPack { int4 e4, m0, m1, m2, m3, m4, m5, m6, m7; };

static __device__ __forceinline__ IdxPack load_idx(
    const int* __restrict__ ne, const int* __restrict__ en, int n) {
  IdxPack I;
  I.e4 = *(const int4*)(ne + (size_t)n * DEG);
  I.m0 = *(const int4*)(en + (size_t)I.e4.x * KPE);
  I.m1 = *(const int4*)(en + (size_t)I.e4.x * KPE + 4);
  I.m2 = *(const int4*)(en + (size_t)I.e4.y * KPE);
  I.m3 = *(const int4*)(en + (size_t)I.e4.y * KPE + 4);
  I.m4 = *(const int4*)(en + (size_t)I.e4.z * KPE);
  I.m5 = *(const int4*)(en + (size_t)I.e4.z * KPE + 4);
  I.m6 = *(const int4*)(en + (size_t)I.e4.w * KPE);
  I.m7 = *(const int4*)(en + (size_t)I.e4.w * KPE + 4);
  return I;
}

#define GLDS(gp, ldsp, sz) __builtin_amdgcn_global_load_lds(               \
    (const __attribute__((address_space(1))) u32*)(gp),                    \
    (__attribute__((address_space(3))) u32*)(ldsp), sz, 0, 0)

static __device__ __forceinline__ void stage_node(
    unsigned char* buf, const IdxPack& I,
    const unsigned short* __restrict__ Kb, const unsigned short* __restrict__ Vb,
    const unsigned short* __restrict__ WeKb, const unsigned short* __restrict__ qb,
    int n, int lane)
{
  int4 mm[8] = {I.m0, I.m1, I.m2, I.m3, I.m4, I.m5, I.m6, I.m7};
  // K rows: 32 x width-4, stride 272 (bank-spread for score b128 reads)
  #pragma unroll
  for (int t = 0; t < 8; ++t) {
    GLDS((const u32*)(Kb + (size_t)mm[t].x * DIM) + lane, buf + OFF_K + (t*4+0)*272, 4);
    GLDS((const u32*)(Kb + (size_t)mm[t].y * DIM) + lane, buf + OFF_K + (t*4+1)*272, 4);
    GLDS((const u32*)(Kb + (size_t)mm[t].z * DIM) + lane, buf + OFF_K + (t*4+2)*272, 4);
    GLDS((const u32*)(Kb + (size_t)mm[t].w * DIM) + lane, buf + OFF_K + (t*4+3)*272, 4);
  }
  // WeK rows: 4 x width-4, stride 272
  GLDS((const u32*)(WeKb + (size_t)I.e4.x * DIM) + lane, buf + OFF_E + 0*272, 4);
  GLDS((const u32*)(WeKb + (size_t)I.e4.y * DIM) + lane, buf + OFF_E + 1*272, 4);
  GLDS((const u32*)(WeKb + (size_t)I.e4.z * DIM) + lane, buf + OFF_E + 2*272, 4);
  GLDS((const u32*)(WeKb + (size_t)I.e4.w * DIM) + lane, buf + OFF_E + 3*272, 4);
  // q row: 1 x width-4
  GLDS((const u32*)(qb + (size_t)n * DIM) + lane, buf + OFF_Q, 4);
  // V rows: 8 x width-16 (each instr stages 4 rows of 256 B, stride 256;
  // ctx reads are b32 at bank=lane%32 -> 2-way, free)
  const int vr = lane >> 4, vc = lane & 15;
  #pragma unroll
  for (int t = 0; t < 8; ++t) {
    int row = (vr & 2) ? ((vr & 1) ? mm[t].w : mm[t].z)
                       : ((vr & 1) ? mm[t].y : mm[t].x);
    GLDS((const u32*)(Vb + (size_t)row * DIM) + vc * 4, buf + OFF_V + t * 1024, 16);
  }
}

static __device__ __forceinline__ void scores_softmax(
    const unsigned char* buf, float* ldsP, int lane)
{
  const int l = lane & 31, half = lane >> 5;
  const unsigned char* krow = buf + OFF_K + l * 272 + half * 128;
  const unsigned char* erow = buf + OFF_E + (l >> 3) * 272 + half * 128;
  const unsigned char* qrow = buf + OFF_Q + half * 128;
  float s[4] = {0.f, 0.f, 0.f, 0.f};
  #pragma unroll
  for (int ch = 0; ch < 8; ++ch) {
    uint4 qc = *(const uint4*)(qrow + ch * 16);
    uint4 kc = *(const uint4*)(krow + ch * 16);
    uint4 ec = *(const uint4*)(erow + ch * 16);
    const int hi = ch >> 1;
    float t = s[hi];
    t = dot2bf(qc.x, kc.x, t); t = dot2bf(qc.x, ec.x, t);
    t = dot2bf(qc.y, kc.y, t); t = dot2bf(qc.y, ec.y, t);
    t = dot2bf(qc.z, kc.z, t); t = dot2bf(qc.z, ec.z, t);
    t = dot2bf(qc.w, kc.w, t); t = dot2bf(qc.w, ec.w, t);
    s[hi] = t;
  }
  #pragma unroll
  for (int hi = 0; hi < 4; ++hi) {
    float vmax = s[hi];
    #pragma unroll
    for (int off = 16; off >= 1; off >>= 1)
      vmax = fmaxf(vmax, __shfl_xor(vmax, off, 32));
    float ex = __expf(s[hi] - vmax);
    float sum = ex;
    #pragma unroll
    for (int off = 16; off >= 1; off >>= 1)
      sum += __shfl_xor(sum, off, 32);
    ldsP[(half * 4 + hi) * 36 + l] = ex / sum;
  }
}

static __device__ __forceinline__ void ctx_store(
    const unsigned char* buf, const float* ldsP, int lane,
    unsigned short* __restrict__ ctxb, int n)
{
  const int h = lane >> 3;
  const int c0 = lane * 2;
  float a0 = 0.f, a1 = 0.f;
  #pragma unroll
  for (int t = 0; t < 8; ++t) {
    float4 p4 = *(const float4*)(ldsP + h * 36 + t * 4);
    u32 v0 = *(const u32*)(buf + OFF_V + (t * 4 + 0) * 256 + lane * 4);
    u32 v1 = *(const u32*)(buf + OFF_V + (t * 4 + 1) * 256 + lane * 4);
    u32 v2 = *(const u32*)(buf + OFF_V + (t * 4 + 2) * 256 + lane * 4);
    u32 v3 = *(const u32*)(buf + OFF_V + (t * 4 + 3) * 256 + lane * 4);
    a0 = fmaf(p4.x, bflo(v0), a0); a1 = fmaf(p4.x, bfhi(v0), a1);
    a0 = fmaf(p4.y, bflo(v1), a0); a1 = fmaf(p4.y, bfhi(v1), a1);
    a0 = fmaf(p4.z, bflo(v2), a0); a1 = fmaf(p4.z, bfhi(v2), a1);
    a0 = fmaf(p4.w, bflo(v3), a0); a1 = fmaf(p4.w, bfhi(v3), a1);
  }
  unsigned int pk = (unsigned int)f2bf(a0) | ((unsigned int)f2bf(a1) << 16);
  __builtin_nontemporal_store(pk, (u32*)(ctxb + (size_t)n * DIM + c0));
}

__global__ __launch_bounds__(64, 2) void attn_kernel(
    const unsigned short* __restrict__ qb, const unsigned short* __restrict__ Kb,
    const unsigned short* __restrict__ Vb, const unsigned short* __restrict__ WeKb,
    const int* __restrict__ nedges, const int* __restrict__ enodes,
    unsigned short* __restrict__ ctxb)
{
  __shared__ __align__(16) unsigned char slds[37664];
  const int lane = threadIdx.x;
  const int n0 = blockIdx.x * 8;
  float* ldsP = (float*)(slds + OFF_P);

  IdxPack ia = load_idx(nedges, enodes, n0 + 0);
  IdxPack ib = load_idx(nedges, enodes, n0 + 1);
  stage_node(slds, ia, Kb, Vb, WeKb, qb, n0 + 0, lane);

#define STEP(kk, IA, IB, HAS2, HAS1, W1, W2)                                   \
  {                                                                            \
    if (HAS2) IA = load_idx(nedges, enodes, n0 + kk + 2);                      \
    if (HAS1) stage_node(slds + ((kk + 1) & 1) * BUFSZ, IB, Kb, Vb, WeKb, qb,  \
                         n0 + kk + 1, lane);                                   \
    asm volatile("s_waitcnt vmcnt(" W1 ")" ::: "memory");                      \
    scores_softmax(slds + ((kk) & 1) * BUFSZ, ldsP, lane);                     \
    asm volatile("s_waitcnt vmcnt(" W2 ")" ::: "memory");                      \
    ctx_store(slds + ((kk) & 1) * BUFSZ, ldsP, lane, ctxb, n0 + kk);           \
  }

  STEP(0, ia, ib, 1, 1, "53", "45")
  STEP(1, ib, ia, 1, 1, "54", "46")
  STEP(2, ia, ib, 1, 1, "54", "46")
  STEP(3, ib, ia, 1, 1, "54", "46")
  STEP(4, ia, ib, 1, 1, "54", "46")
  STEP(5, ib, ia, 1, 1, "54", "46")
  STEP(6, ia, ib, 0, 1, "54", "46")
  STEP(7, ib, ia, 0, 0, "9",  "1")
#undef STEP
}

// ---------------- G4: ctx @ Wo^T + bo, ReLU -> out fp32 -------
__global__ __launch_bounds__(256) void g4_kernel(
    const unsigned short* __restrict__ ctxb, const unsigned short* __restrict__ Wob,
    const float* __restrict__ bo, float* __restrict__ out)
{
  const int wave = threadIdx.x >> 6, lane = threadIdx.x & 63;
  const int r16 = lane & 15, quad = lane >> 4;
  const int m0 = blockIdx.x * 64 + wave * 16;
  const int n0 = blockIdx.y * 64;

  f32x4 acc[4];
  const f32x4 z = {0.f, 0.f, 0.f, 0.f};
  acc[0] = z; acc[1] = z; acc[2] = z; acc[3] = z;

  #pragma unroll
  for (int kk = 0; kk < 4; ++kk) {
    u16x8 au = *(const u16x8*)(ctxb + (size_t)(m0 + r16) * DIM + kk * 32 + quad * 8);
    bf16x8 av = __builtin_bit_cast(bf16x8, au);
    #pragma unroll
    for (int s = 0; s < 4; ++s) {
      u16x8 bu = *(const u16x8*)(Wob + (size_t)(n0 + s * 16 + r16) * DIM + kk * 32 + quad * 8);
      acc[s] = __builtin_amdgcn_mfma_f32_16x16x32_bf16(
          av, __builtin_bit_cast(bf16x8, bu), acc[s], 0, 0, 0);
    }
  }

  #pragma unroll
  for (int s = 0; s < 4; ++s) {
    int j = n0 + s * 16 + r16;
    float bias = bo[j];
    #pragma unroll
    for (int r = 0; r < 4; ++r) {
      int m = m0 + quad * 4 + r;
      float v = acc[s][r] + bias;
      out[(size_t)m * DIM + j] = v > 0.f ? v : 0.f;
    }
  }
}

extern "C" void kernel_launch(void* const* d_in, const int* in_sizes, int n_in,
                              void* d_out, int out_size, void* d_ws, size_t ws_size,
                              hipStream_t stream)
{
  const float* x     = (const float*)d_in[0];
  const float* ea    = (const float*)d_in[1];
  const int* nedges  = (const int*)d_in[2];
  const int* enodes  = (const int*)d_in[3];
  const float* Wlin  = (const float*)d_in[4];
  const float* Wedge = (const float*)d_in[5];
  const float* Wq    = (const float*)d_in[6];
  const float* Wk    = (const float*)d_in[7];
  const float* Wv    = (const float*)d_in[8];
  const float* bq    = (const float*)d_in[9];
  const float* bk    = (const float*)d_in[10];
  const float* bv    = (const float*)d_in[11];
  const float* Wo    = (const float*)d_in[12];
  const float* bo    = (const float*)d_in[13];
  float* out = (float*)d_out;

  unsigned short* wsp = (unsigned short*)d_ws;
  unsigned short* CW   = wsp;  wsp += 384 * 128;
  unsigned short* CWE  = wsp;  wsp += 128 * 64;
  unsigned short* Wob  = wsp;  wsp += 128 * 128;
  unsigned short* qb   = wsp;  wsp += (size_t)N_NODES * DIM;
  unsigned short* Kb   = wsp;  wsp += (size_t)N_NODES * DIM;
  unsigned short* Vb   = wsp;  wsp += (size_t)N_NODES * DIM;
  unsigned short* WeKb = wsp;  wsp += (size_t)N_EDGES * DIM;
  unsigned short* ctxb = wsp;  wsp += (size_t)N_NODES * DIM;

  wprep_kernel<<<dim3(288), dim3(256), 0, stream>>>(Wq, Wk, Wv, Wlin, Wedge, Wo, CW, CWE, Wob);
  g12_kernel<<<dim3(1024), dim3(256), 0, stream>>>(x, CW, bq, bv, qb, Kb, Vb, ea, CWE, bk, WeKb);
  attn_kernel<<<dim3(4096), dim3(64), 0, stream>>>(qb, Kb, Vb, WeKb, nedges, enodes, ctxb);
  g4_kernel<<<dim3(512, 2), dim3(256), 0, stream>>>(ctxb, Wob, bo, out);
}

// Round 9
// 207.675 us; speedup vs baseline: 1.3785x; 1.3785x over previous
//
#include <hip/hip_runtime.h>
#include <hip/hip_cooperative_groups.h>

namespace cg = cooperative_groups;

#define N_NODES 32768
#define N_EDGES 16384
#define DEG 4
#define KPE 8
#define DIM 128
#define EDIM 64

#define GRID_BLOCKS 512
#define ATTN_WAVES (GRID_BLOCKS * 4)   // 2048 waves -> 16 nodes/wave

// per-wave attn LDS region: K(32x272) + E(4x272) + P(8x36 f32)
#define AOFF_K 0
#define AOFF_E 8704
#define AOFF_P 9792
#define AWAVESZ 10944

typedef float f32x4 __attribute__((ext_vector_type(4)));
typedef __bf16 bf16x8 __attribute__((ext_vector_type(8)));
typedef __bf16 bf16x2 __attribute__((ext_vector_type(2)));
typedef unsigned short u16x8 __attribute__((ext_vector_type(8)));
typedef unsigned int u32;
typedef unsigned int u32x4 __attribute__((ext_vector_type(4)));

static __device__ __forceinline__ unsigned short f2bf(float f) {
  union { float f; unsigned int u; } v; v.f = f;
  unsigned int r = (v.u + 0x7FFFu + ((v.u >> 16) & 1u)) >> 16;
  return (unsigned short)r;
}
static __device__ __forceinline__ float bflo(unsigned int v) {
  union { unsigned int u; float f; } x; x.u = v << 16; return x.f;
}
static __device__ __forceinline__ float bfhi(unsigned int v) {
  union { unsigned int u; float f; } x; x.u = v & 0xffff0000u; return x.f;
}

#if __has_builtin(__builtin_amdgcn_fdot2_f32_bf16)
static __device__ __forceinline__ float dot2bf(unsigned int a, unsigned int b, float c) {
  return __builtin_amdgcn_fdot2_f32_bf16(
      __builtin_bit_cast(bf16x2, a), __builtin_bit_cast(bf16x2, b), c, false);
}
#else
static __device__ __forceinline__ float dot2bf(unsigned int a, unsigned int b, float c) {
  c = fmaf(bflo(a), bflo(b), c);
  return fmaf(bfhi(a), bfhi(b), c);
}
#endif

#define GLDS(gp, ldsp, sz) __builtin_amdgcn_global_load_lds(               \
    (const __attribute__((address_space(1))) u32*)(gp),                    \
    (__attribute__((address_space(3))) u32*)(ldsp), sz, 0, 0)

// ---------------- shared device bodies ----------------

static __device__ __forceinline__ void wprep_elem(
    int id, const float* __restrict__ Wq, const float* __restrict__ Wk,
    const float* __restrict__ Wv, const float* __restrict__ Wlin,
    const float* __restrict__ Wedge, const float* __restrict__ Wo,
    unsigned short* __restrict__ CW, unsigned short* __restrict__ CWE,
    unsigned short* __restrict__ Wob)
{
  if (id < 384 * 128) {
    int j = id >> 7, i = id & 127;
    const float* wrow; float scale = 1.0f;
    if (j < 128)      { wrow = Wq + j * 128; scale = 0.25f; }
    else if (j < 256) { wrow = Wk + (j - 128) * 128; }
    else              { wrow = Wv + (j - 256) * 128; }
    float s = 0.f;
    #pragma unroll 8
    for (int m = 0; m < 128; ++m) s += wrow[m] * Wlin[m * 128 + i];
    CW[id] = f2bf(s * scale);
  } else if (id < 384 * 128 + 128 * 64) {
    int id2 = id - 384 * 128; int j = id2 >> 6, t = id2 & 63;
    float s = 0.f;
    #pragma unroll 8
    for (int m = 0; m < 128; ++m) s += Wk[j * 128 + m] * Wedge[m * 64 + t];
    CWE[id2] = f2bf(s);
  } else if (id < 384 * 128 + 128 * 64 + 128 * 128) {
    int id3 = id - (384 * 128 + 128 * 64);
    Wob[id3] = f2bf(Wo[id3]);
  }
}

static __device__ __forceinline__ void g12_unit(
    int unit, int wave, int lane,
    const float* __restrict__ x, const unsigned short* __restrict__ CW,
    const float* __restrict__ bq, const float* __restrict__ bv,
    unsigned short* __restrict__ qb, unsigned short* __restrict__ Kb,
    unsigned short* __restrict__ Vb,
    const float* __restrict__ ea, const unsigned short* __restrict__ CWE,
    const float* __restrict__ bk, unsigned short* __restrict__ WeKb)
{
  const int r16 = lane & 15, quad = lane >> 4;
  if (unit < 512) {
    const int m0 = unit * 64 + wave * 16;
    u16x8 av[4];
    const float* arow = x + (size_t)(m0 + r16) * DIM + quad * 8;
    #pragma unroll
    for (int kk = 0; kk < 4; ++kk) {
      float4 a0 = *(const float4*)(arow + kk * 32);
      float4 a1 = *(const float4*)(arow + kk * 32 + 4);
      u16x8 au;
      au[0] = f2bf(a0.x); au[1] = f2bf(a0.y); au[2] = f2bf(a0.z); au[3] = f2bf(a0.w);
      au[4] = f2bf(a1.x); au[5] = f2bf(a1.y); au[6] = f2bf(a1.z); au[7] = f2bf(a1.w);
      av[kk] = au;
    }
    #pragma unroll
    for (int g = 0; g < 6; ++g) {
      f32x4 acc[4];
      const f32x4 z = {0.f, 0.f, 0.f, 0.f};
      acc[0] = z; acc[1] = z; acc[2] = z; acc[3] = z;
      #pragma unroll
      for (int kk = 0; kk < 4; ++kk) {
        #pragma unroll
        for (int s = 0; s < 4; ++s) {
          u16x8 bu = *(const u16x8*)(CW + (size_t)(g * 64 + s * 16 + r16) * DIM + kk * 32 + quad * 8);
          acc[s] = __builtin_amdgcn_mfma_f32_16x16x32_bf16(
              __builtin_bit_cast(bf16x8, av[kk]), __builtin_bit_cast(bf16x8, bu), acc[s], 0, 0, 0);
        }
      }
      const int arr = g >> 1;               // 0:q 1:K 2:V
      const int colbase = (g & 1) * 64;
      unsigned short* dst = arr == 0 ? qb : (arr == 1 ? Kb : Vb);
      #pragma unroll
      for (int s = 0; s < 4; ++s) {
        int j = colbase + s * 16 + r16;
        float bias = arr == 0 ? 0.25f * bq[j] : (arr == 2 ? bv[j] : 0.f);
        #pragma unroll
        for (int r = 0; r < 4; ++r) {
          int m = m0 + quad * 4 + r;
          dst[(size_t)m * DIM + j] = f2bf(acc[s][r] + bias);
        }
      }
    }
  } else {
    const int idx = unit - 512;
    const int m0 = (idx >> 1) * 64 + wave * 16;
    const int n0 = (idx & 1) * 64;
    f32x4 acc[4];
    const f32x4 z = {0.f, 0.f, 0.f, 0.f};
    acc[0] = z; acc[1] = z; acc[2] = z; acc[3] = z;
    const float* arow = ea + (size_t)(m0 + r16) * EDIM + quad * 8;
    #pragma unroll
    for (int kk = 0; kk < 2; ++kk) {
      float4 a0 = *(const float4*)(arow + kk * 32);
      float4 a1 = *(const float4*)(arow + kk * 32 + 4);
      u16x8 au;
      au[0] = f2bf(a0.x); au[1] = f2bf(a0.y); au[2] = f2bf(a0.z); au[3] = f2bf(a0.w);
      au[4] = f2bf(a1.x); au[5] = f2bf(a1.y); au[6] = f2bf(a1.z); au[7] = f2bf(a1.w);
      bf16x8 av = __builtin_bit_cast(bf16x8, au);
      #pragma unroll
      for (int s = 0; s < 4; ++s) {
        u16x8 bu = *(const u16x8*)(CWE + (size_t)(n0 + s * 16 + r16) * EDIM + kk * 32 + quad * 8);
        acc[s] = __builtin_amdgcn_mfma_f32_16x16x32_bf16(
            av, __builtin_bit_cast(bf16x8, bu), acc[s], 0, 0, 0);
      }
    }
    #pragma unroll
    for (int s = 0; s < 4; ++s) {
      int j = n0 + s * 16 + r16;
      float bias = bk[j];
      #pragma unroll
      for (int r = 0; r < 4; ++r) {
        int m = m0 + quad * 4 + r;
        WeKb[(size_t)m * DIM + j] = f2bf(acc[s][r] + bias);
      }
    }
  }
}

// r6 attention body: one wave, one node, per-wave LDS region abuf.
static __device__ __forceinline__ void attn_node(
    int n, unsigned char* __restrict__ abuf, int lane,
    const unsigned short* __restrict__ qb, const unsigned short* __restrict__ Kb,
    const unsigned short* __restrict__ Vb, const unsigned short* __restrict__ WeKb,
    const int* __restrict__ nedges, const int* __restrict__ enodes,
    unsigned short* __restrict__ ctxb)
{
  float* ldsP = (float*)(abuf + AOFF_P);
  const int l = lane & 31, half = lane >> 5;
  const int h = lane >> 3;
  const int c0 = lane * 2;

  int4 e4 = *(const int4*)(nedges + (size_t)n * DEG);
  int4 m0i = *(const int4*)(enodes + (size_t)e4.x * KPE);
  int4 m1i = *(const int4*)(enodes + (size_t)e4.x * KPE + 4);
  int4 m2i = *(const int4*)(enodes + (size_t)e4.y * KPE);
  int4 m3i = *(const int4*)(enodes + (size_t)e4.y * KPE + 4);
  int4 m4i = *(const int4*)(enodes + (size_t)e4.z * KPE);
  int4 m5i = *(const int4*)(enodes + (size_t)e4.z * KPE + 4);
  int4 m6i = *(const int4*)(enodes + (size_t)e4.w * KPE);
  int4 m7i = *(const int4*)(enodes + (size_t)e4.w * KPE + 4);

#define STAGE(off, table, row) GLDS((const u32*)((table) + (size_t)(row) * DIM) + lane, abuf + (off), 4)
  STAGE(AOFF_K + 0  * 272, Kb, m0i.x); STAGE(AOFF_K + 1  * 272, Kb, m0i.y);
  STAGE(AOFF_K + 2  * 272, Kb, m0i.z); STAGE(AOFF_K + 3  * 272, Kb, m0i.w);
  STAGE(AOFF_K + 4  * 272, Kb, m1i.x); STAGE(AOFF_K + 5  * 272, Kb, m1i.y);
  STAGE(AOFF_K + 6  * 272, Kb, m1i.z); STAGE(AOFF_K + 7  * 272, Kb, m1i.w);
  STAGE(AOFF_K + 8  * 272, Kb, m2i.x); STAGE(AOFF_K + 9  * 272, Kb, m2i.y);
  STAGE(AOFF_K + 10 * 272, Kb, m2i.z); STAGE(AOFF_K + 11 * 272, Kb, m2i.w);
  STAGE(AOFF_K + 12 * 272, Kb, m3i.x); STAGE(AOFF_K + 13 * 272, Kb, m3i.y);
  STAGE(AOFF_K + 14 * 272, Kb, m3i.z); STAGE(AOFF_K + 15 * 272, Kb, m3i.w);
  STAGE(AOFF_K + 16 * 272, Kb, m4i.x); STAGE(AOFF_K + 17 * 272, Kb, m4i.y);
  STAGE(AOFF_K + 18 * 272, Kb, m4i.z); STAGE(AOFF_K + 19 * 272, Kb, m4i.w);
  STAGE(AOFF_K + 20 * 272, Kb, m5i.x); STAGE(AOFF_K + 21 * 272, Kb, m5i.y);
  STAGE(AOFF_K + 22 * 272, Kb, m5i.z); STAGE(AOFF_K + 23 * 272, Kb, m5i.w);
  STAGE(AOFF_K + 24 * 272, Kb, m6i.x); STAGE(AOFF_K + 25 * 272, Kb, m6i.y);
  STAGE(AOFF_K + 26 * 272, Kb, m6i.z); STAGE(AOFF_K + 27 * 272, Kb, m6i.w);
  STAGE(AOFF_K + 28 * 272, Kb, m7i.x); STAGE(AOFF_K + 29 * 272, Kb, m7i.y);
  STAGE(AOFF_K + 30 * 272, Kb, m7i.z); STAGE(AOFF_K + 31 * 272, Kb, m7i.w);
  STAGE(AOFF_E + 0 * 272, WeKb, e4.x); STAGE(AOFF_E + 1 * 272, WeKb, e4.y);
  STAGE(AOFF_E + 2 * 272, WeKb, e4.z); STAGE(AOFF_E + 3 * 272, WeKb, e4.w);
#undef STAGE

  const u32x4* qp = (const u32x4*)(qb + (size_t)n * DIM + half * 64);
  u32x4 qv[8];
  #pragma unroll
  for (int ch = 0; ch < 8; ++ch) qv[ch] = __builtin_nontemporal_load(qp + ch);

  asm volatile("" ::: "memory");

  u32 vv[32];
#define VLOAD(t, row) vv[t] = *(const u32*)(Vb + (size_t)(row) * DIM + c0)
  VLOAD(0,  m0i.x); VLOAD(1,  m0i.y); VLOAD(2,  m0i.z); VLOAD(3,  m0i.w);
  VLOAD(4,  m1i.x); VLOAD(5,  m1i.y); VLOAD(6,  m1i.z); VLOAD(7,  m1i.w);
  VLOAD(8,  m2i.x); VLOAD(9,  m2i.y); VLOAD(10, m2i.z); VLOAD(11, m2i.w);
  VLOAD(12, m3i.x); VLOAD(13, m3i.y); VLOAD(14, m3i.z); VLOAD(15, m3i.w);
  VLOAD(16, m4i.x); VLOAD(17, m4i.y); VLOAD(18, m4i.z); VLOAD(19, m4i.w);
  VLOAD(20, m5i.x); VLOAD(21, m5i.y); VLOAD(22, m5i.z); VLOAD(23, m5i.w);
  VLOAD(24, m6i.x); VLOAD(25, m6i.y); VLOAD(26, m6i.z); VLOAD(27, m6i.w);
  VLOAD(28, m7i.x); VLOAD(29, m7i.y); VLOAD(30, m7i.z); VLOAD(31, m7i.w);
#undef VLOAD

  asm volatile("s_waitcnt vmcnt(32)" ::: "memory");

  const unsigned char* krow = abuf + AOFF_K + l * 272 + half * 128;
  const unsigned char* erow = abuf + AOFF_E + (l >> 3) * 272 + half * 128;
  float s[4] = {0.f, 0.f, 0.f, 0.f};
  #pragma unroll
  for (int ch = 0; ch < 8; ++ch) {
    uint4 kc = *(const uint4*)(krow + ch * 16);
    uint4 ec = *(const uint4*)(erow + ch * 16);
    const int hi = ch >> 1;
    float t = s[hi];
    t = dot2bf(qv[ch].x, kc.x, t); t = dot2bf(qv[ch].x, ec.x, t);
    t = dot2bf(qv[ch].y, kc.y, t); t = dot2bf(qv[ch].y, ec.y, t);
    t = dot2bf(qv[ch].z, kc.z, t); t = dot2bf(qv[ch].z, ec.z, t);
    t = dot2bf(qv[ch].w, kc.w, t); t = dot2bf(qv[ch].w, ec.w, t);
    s[hi] = t;
  }

  #pragma unroll
  for (int hi = 0; hi < 4; ++hi) {
    float vmax = s[hi];
    #pragma unroll
    for (int off = 16; off >= 1; off >>= 1)
      vmax = fmaxf(vmax, __shfl_xor(vmax, off, 32));
    float ex = __expf(s[hi] - vmax);
    float sum = ex;
    #pragma unroll
    for (int off = 16; off >= 1; off >>= 1)
      sum += __shfl_xor(sum, off, 32);
    ldsP[(half * 4 + hi) * 36 + l] = ex / sum;
  }

  float a0 = 0.f, a1 = 0.f;
  #pragma unroll
  for (int t = 0; t < 8; ++t) {
    float4 p4 = *(const float4*)(ldsP + h * 36 + t * 4);
    a0 = fmaf(p4.x, bflo(vv[t * 4 + 0]), a0); a1 = fmaf(p4.x, bfhi(vv[t * 4 + 0]), a1);
    a0 = fmaf(p4.y, bflo(vv[t * 4 + 1]), a0); a1 = fmaf(p4.y, bfhi(vv[t * 4 + 1]), a1);
    a0 = fmaf(p4.z, bflo(vv[t * 4 + 2]), a0); a1 = fmaf(p4.z, bfhi(vv[t * 4 + 2]), a1);
    a0 = fmaf(p4.w, bflo(vv[t * 4 + 3]), a0); a1 = fmaf(p4.w, bfhi(vv[t * 4 + 3]), a1);
  }
  unsigned int pk = (unsigned int)f2bf(a0) | ((unsigned int)f2bf(a1) << 16);
  __builtin_nontemporal_store(pk, (u32*)(ctxb + (size_t)n * DIM + c0));
}

static __device__ __forceinline__ void g4_unit(
    int unit, int wave, int lane,
    const unsigned short* __restrict__ ctxb, const unsigned short* __restrict__ Wob,
    const float* __restrict__ bo, float* __restrict__ out)
{
  const int r16 = lane & 15, quad = lane >> 4;
  const int bx = unit & 511, by = unit >> 9;
  const int m0 = bx * 64 + wave * 16;
  const int n0 = by * 64;
  f32x4 acc[4];
  const f32x4 z = {0.f, 0.f, 0.f, 0.f};
  acc[0] = z; acc[1] = z; acc[2] = z; acc[3] = z;
  #pragma unroll
  for (int kk = 0; kk < 4; ++kk) {
    u16x8 au = *(const u16x8*)(ctxb + (size_t)(m0 + r16) * DIM + kk * 32 + quad * 8);
    bf16x8 av = __builtin_bit_cast(bf16x8, au);
    #pragma unroll
    for (int s = 0; s < 4; ++s) {
      u16x8 bu = *(const u16x8*)(Wob + (size_t)(n0 + s * 16 + r16) * DIM + kk * 32 + quad * 8);
      acc[s] = __builtin_amdgcn_mfma_f32_16x16x32_bf16(
          av, __builtin_bit_cast(bf16x8, bu), acc[s], 0, 0, 0);
    }
  }
  #pragma unroll
  for (int s = 0; s < 4; ++s) {
    int j = n0 + s * 16 + r16;
    float bias = bo[j];
    #pragma unroll
    for (int r = 0; r < 4; ++r) {
      int m = m0 + quad * 4 + r;
      float v = acc[s][r] + bias;
      out[(size_t)m * DIM + j] = v > 0.f ? v : 0.f;
    }
  }
}

// ---------------- fused cooperative kernel ----------------
__global__ __launch_bounds__(256, 2) void fused_kernel(
    const float* __restrict__ x, const float* __restrict__ ea,
    const int* __restrict__ nedges, const int* __restrict__ enodes,
    const float* __restrict__ Wlin, const float* __restrict__ Wedge,
    const float* __restrict__ Wq, const float* __restrict__ Wk,
    const float* __restrict__ Wv, const float* __restrict__ bq,
    const float* __restrict__ bk, const float* __restrict__ bv,
    const float* __restrict__ Wo, const float* __restrict__ bo,
    unsigned short* __restrict__ CW, unsigned short* __restrict__ CWE,
    unsigned short* __restrict__ Wob, unsigned short* __restrict__ qb,
    unsigned short* __restrict__ Kb, unsigned short* __restrict__ Vb,
    unsigned short* __restrict__ WeKb, unsigned short* __restrict__ ctxb,
    float* __restrict__ out)
{
  __shared__ __align__(16) unsigned char slds[AWAVESZ * 4];
  cg::grid_group grid = cg::this_grid();
  const int wave = threadIdx.x >> 6, lane = threadIdx.x & 63;

  // Phase A: weight combine (512*256 threads cover 73728 elems)
  wprep_elem(blockIdx.x * 256 + threadIdx.x, Wq, Wk, Wv, Wlin, Wedge, Wo, CW, CWE, Wob);
  grid.sync();

  // Phase B: projections
  for (int unit = blockIdx.x; unit < 1024; unit += GRID_BLOCKS)
    g12_unit(unit, wave, lane, x, CW, bq, bv, qb, Kb, Vb, ea, CWE, bk, WeKb);
  grid.sync();

  // Phase C: attention, 16 nodes per wave
  {
    unsigned char* abuf = slds + wave * AWAVESZ;
    const int wv = blockIdx.x * 4 + wave;
    for (int n = wv; n < N_NODES; n += ATTN_WAVES)
      attn_node(n, abuf, lane, qb, Kb, Vb, WeKb, nedges, enodes, ctxb);
  }
  grid.sync();

  // Phase D: output projection + ReLU
  for (int unit = blockIdx.x; unit < 1024; unit += GRID_BLOCKS)
    g4_unit(unit, wave, lane, ctxb, Wob, bo, out);
}

// ---------------- fallback kernels (r6-proven, lower-ramp attn) ----------------
__global__ __launch_bounds__(256) void wprep_kernel(
    const float* __restrict__ Wq, const float* __restrict__ Wk,
    const float* __restrict__ Wv, const float* __restrict__ Wlin,
    const float* __restrict__ Wedge, const float* __restrict__ Wo,
    unsigned short* __restrict__ CW, unsigned short* __restrict__ CWE,
    unsigned short* __restrict__ Wob)
{
  wprep_elem(blockIdx.x * 256 + threadIdx.x, Wq, Wk, Wv, Wlin, Wedge, Wo, CW, CWE, Wob);
}

__global__ __launch_bounds__(256) void g12_kernel(
    const float* __restrict__ x, const unsigned short* __restrict__ CW,
    const float* __restrict__ bq, const float* __restrict__ bv,
    unsigned short* __restrict__ qb, unsigned short* __restrict__ Kb,
    unsigned short* __restrict__ Vb,
    const float* __restrict__ ea, const unsigned short* __restrict__ CWE,
    const float* __restrict__ bk, unsigned short* __restrict__ WeKb)
{
  g12_unit(blockIdx.x, threadIdx.x >> 6, threadIdx.x & 63,
           x, CW, bq, bv, qb, Kb, Vb, ea, CWE, bk, WeKb);
}

__global__ __launch_bounds__(256, 2) void attn_kernel(
    const unsigned short* __restrict__ qb, const unsigned short* __restrict__ Kb,
    const unsigned short* __restrict__ Vb, const unsigned short* __restrict__ WeKb,
    const int* __restrict__ nedges, const int* __restrict__ enodes,
    unsigned short* __restrict__ ctxb)
{
  __shared__ __align__(16) unsigned char slds[AWAVESZ * 4];
  const int wave = threadIdx.x >> 6, lane = threadIdx.x & 63;
  attn_node(blockIdx.x * 4 + wave, slds + wave * AWAVESZ, lane,
            qb, Kb, Vb, WeKb, nedges, enodes, ctxb);
}

__global__ __launch_bounds__(256) void g4_kernel(
    const unsigned short* __restrict__ ctxb, const unsigned short* __restrict__ Wob,
    const float* __restrict__ bo, float* __restrict__ out)
{
  g4_unit(blockIdx.x, threadIdx.x >> 6, threadIdx.x & 63, ctxb, Wob, bo, out);
}

extern "C" void kernel_launch(void* const* d_in, const int* in_sizes, int n_in,
                              void* d_out, int out_size, void* d_ws, size_t ws_size,
                              hipStream_t stream)
{
  const float* x     = (const float*)d_in[0];
  const float* ea    = (const float*)d_in[1];
  const int* nedges  = (const int*)d_in[2];
  const int* enodes  = (const int*)d_in[3];
  const float* Wlin  = (const float*)d_in[4];
  const float* Wedge = (const float*)d_in[5];
  const float* Wq    = (const float*)d_in[6];
  const float* Wk    = (const float*)d_in[7];
  const float* Wv    = (const float*)d_in[8];
  const float* bq    = (const float*)d_in[9];
  const float* bk    = (const float*)d_in[10];
  const float* bv    = (const float*)d_in[11];
  const float* Wo    = (const float*)d_in[12];
  const float* bo    = (const float*)d_in[13];
  float* out = (float*)d_out;

  unsigned short* wsp = (unsigned short*)d_ws;
  unsigned short* CW   = wsp;  wsp += 384 * 128;
  unsigned short* CWE  = wsp;  wsp += 128 * 64;
  unsigned short* Wob  = wsp;  wsp += 128 * 128;
  unsigned short* qb   = wsp;  wsp += (size_t)N_NODES * DIM;
  unsigned short* Kb   = wsp;  wsp += (size_t)N_NODES * DIM;
  unsigned short* Vb   = wsp;  wsp += (size_t)N_NODES * DIM;
  unsigned short* WeKb = wsp;  wsp += (size_t)N_EDGES * DIM;
  unsigned short* ctxb = wsp;  wsp += (size_t)N_NODES * DIM;

  // Capture-safe pure host query: cooperative only if 2 blocks/CU co-resident.
  int maxb = 0;
  hipError_t qerr = hipOccupancyMaxActiveBlocksPerMultiprocessor(
      &maxb, (const void*)fused_kernel, 256, 0);
  bool coop = (qerr == hipSuccess && maxb >= 2);

  if (coop) {
    void* args[] = {
      (void*)&x, (void*)&ea, (void*)&nedges, (void*)&enodes,
      (void*)&Wlin, (void*)&Wedge, (void*)&Wq, (void*)&Wk, (void*)&Wv,
      (void*)&bq, (void*)&bk, (void*)&bv, (void*)&Wo, (void*)&bo,
      (void*)&CW, (void*)&CWE, (void*)&Wob, (void*)&qb, (void*)&Kb,
      (void*)&Vb, (void*)&WeKb, (void*)&ctxb, (void*)&out
    };
    hipError_t le = hipLaunchCooperativeKernel((const void*)fused_kernel,
                                               dim3(GRID_BLOCKS), dim3(256),
                                               args, 0, stream);
    if (le == hipSuccess) return;
  }

  // Fallback: proven 4-kernel path (attn at 8192 blocks to cut dispatch ramp).
  wprep_kernel<<<dim3(288), dim3(256), 0, stream>>>(Wq, Wk, Wv, Wlin, Wedge, Wo, CW, CWE, Wob);
  g12_kernel<<<dim3(1024), dim3(256), 0, stream>>>(x, CW, bq, bv, qb, Kb, Vb, ea, CWE, bk, WeKb);
  attn_kernel<<<dim3(8192), dim3(256), 0, stream>>>(qb, Kb, Vb, WeKb, nedges, enodes, ctxb);
  g4_kernel<<<dim3(1024), dim3(256), 0, stream>>>(ctxb, Wob, bo, out);
}

// Round 10
// 205.692 us; speedup vs baseline: 1.3918x; 1.0096x over previous
//
#include <hip/hip_runtime.h>

#define N_NODES 32768
#define N_EDGES 16384
#define DEG 4
#define KPE 8
#define DIM 128
#define EDIM 64

// per-wave attn LDS region: K(32x272) + E(4x272) + P(8x36 f32)
#define AOFF_K 0
#define AOFF_E 8704
#define AOFF_P 9792
#define AWAVESZ 10944

typedef float f32x4 __attribute__((ext_vector_type(4)));
typedef __bf16 bf16x8 __attribute__((ext_vector_type(8)));
typedef __bf16 bf16x2 __attribute__((ext_vector_type(2)));
typedef unsigned short u16x8 __attribute__((ext_vector_type(8)));
typedef unsigned int u32;
typedef unsigned int u32x4 __attribute__((ext_vector_type(4)));

static __device__ __forceinline__ unsigned short f2bf(float f) {
  union { float f; unsigned int u; } v; v.f = f;
  unsigned int r = (v.u + 0x7FFFu + ((v.u >> 16) & 1u)) >> 16;
  return (unsigned short)r;
}
static __device__ __forceinline__ float bflo(unsigned int v) {
  union { unsigned int u; float f; } x; x.u = v << 16; return x.f;
}
static __device__ __forceinline__ float bfhi(unsigned int v) {
  union { unsigned int u; float f; } x; x.u = v & 0xffff0000u; return x.f;
}

#if __has_builtin(__builtin_amdgcn_fdot2_f32_bf16)
static __device__ __forceinline__ float dot2bf(unsigned int a, unsigned int b, float c) {
  return __builtin_amdgcn_fdot2_f32_bf16(
      __builtin_bit_cast(bf16x2, a), __builtin_bit_cast(bf16x2, b), c, false);
}
#else
static __device__ __forceinline__ float dot2bf(unsigned int a, unsigned int b, float c) {
  c = fmaf(bflo(a), bflo(b), c);
  return fmaf(bfhi(a), bfhi(b), c);
}
#endif

#define GLDS(gp, ldsp, sz) __builtin_amdgcn_global_load_lds(               \
    (const __attribute__((address_space(1))) u32*)(gp),                    \
    (__attribute__((address_space(3))) u32*)(ldsp), sz, 0, 0)

// ---------------- wprep: CW=[0.25*Wq@Wlin; Wk@Wlin; Wv@Wlin], CWE=Wk@Wedge,
// Wob = bf16(Wo) ----------------
__global__ __launch_bounds__(256) void wprep_kernel(
    const float* __restrict__ Wq, const float* __restrict__ Wk,
    const float* __restrict__ Wv, const float* __restrict__ Wlin,
    const float* __restrict__ Wedge, const float* __restrict__ Wo,
    unsigned short* __restrict__ CW, unsigned short* __restrict__ CWE,
    unsigned short* __restrict__ Wob)
{
  int id = blockIdx.x * 256 + threadIdx.x;
  if (id < 384 * 128) {
    int j = id >> 7, i = id & 127;
    const float* wrow; float scale = 1.0f;
    if (j < 128)      { wrow = Wq + j * 128; scale = 0.25f; }
    else if (j < 256) { wrow = Wk + (j - 128) * 128; }
    else              { wrow = Wv + (j - 256) * 128; }
    float s = 0.f;
    #pragma unroll 8
    for (int m = 0; m < 128; ++m) s += wrow[m] * Wlin[m * 128 + i];
    CW[id] = f2bf(s * scale);
  } else if (id < 384 * 128 + 128 * 64) {
    int id2 = id - 384 * 128; int j = id2 >> 6, t = id2 & 63;
    float s = 0.f;
    #pragma unroll 8
    for (int m = 0; m < 128; ++m) s += Wk[j * 128 + m] * Wedge[m * 64 + t];
    CWE[id2] = f2bf(s);
  } else if (id < 384 * 128 + 128 * 64 + 128 * 128) {
    int id3 = id - (384 * 128 + 128 * 64);
    Wob[id3] = f2bf(Wo[id3]);
  }
}

// ---------------- g12: x -> q/K/V tables;  ea -> WeK table ----------------
__global__ __launch_bounds__(256) void g12_kernel(
    const float* __restrict__ x, const unsigned short* __restrict__ CW,
    const float* __restrict__ bq, const float* __restrict__ bv,
    unsigned short* __restrict__ qb, unsigned short* __restrict__ Kb,
    unsigned short* __restrict__ Vb,
    const float* __restrict__ ea, const unsigned short* __restrict__ CWE,
    const float* __restrict__ bk, unsigned short* __restrict__ WeKb)
{
  const int wave = threadIdx.x >> 6, lane = threadIdx.x & 63;
  const int r16 = lane & 15, quad = lane >> 4;
  const int unit = blockIdx.x;

  if (unit < 512) {
    const int m0 = unit * 64 + wave * 16;
    u16x8 av[4];
    const float* arow = x + (size_t)(m0 + r16) * DIM + quad * 8;
    #pragma unroll
    for (int kk = 0; kk < 4; ++kk) {
      float4 a0 = *(const float4*)(arow + kk * 32);
      float4 a1 = *(const float4*)(arow + kk * 32 + 4);
      u16x8 au;
      au[0] = f2bf(a0.x); au[1] = f2bf(a0.y); au[2] = f2bf(a0.z); au[3] = f2bf(a0.w);
      au[4] = f2bf(a1.x); au[5] = f2bf(a1.y); au[6] = f2bf(a1.z); au[7] = f2bf(a1.w);
      av[kk] = au;
    }
    #pragma unroll
    for (int g = 0; g < 6; ++g) {
      f32x4 acc[4];
      const f32x4 z = {0.f, 0.f, 0.f, 0.f};
      acc[0] = z; acc[1] = z; acc[2] = z; acc[3] = z;
      #pragma unroll
      for (int kk = 0; kk < 4; ++kk) {
        #pragma unroll
        for (int s = 0; s < 4; ++s) {
          u16x8 bu = *(const u16x8*)(CW + (size_t)(g * 64 + s * 16 + r16) * DIM + kk * 32 + quad * 8);
          acc[s] = __builtin_amdgcn_mfma_f32_16x16x32_bf16(
              __builtin_bit_cast(bf16x8, av[kk]), __builtin_bit_cast(bf16x8, bu), acc[s], 0, 0, 0);
        }
      }
      const int arr = g >> 1;               // 0:q 1:K 2:V
      const int colbase = (g & 1) * 64;
      unsigned short* dst = arr == 0 ? qb : (arr == 1 ? Kb : Vb);
      #pragma unroll
      for (int s = 0; s < 4; ++s) {
        int j = colbase + s * 16 + r16;
        float bias = arr == 0 ? 0.25f * bq[j] : (arr == 2 ? bv[j] : 0.f);
        #pragma unroll
        for (int r = 0; r < 4; ++r) {
          int m = m0 + quad * 4 + r;
          dst[(size_t)m * DIM + j] = f2bf(acc[s][r] + bias);
        }
      }
    }
  } else {
    const int idx = unit - 512;
    const int m0 = (idx >> 1) * 64 + wave * 16;
    const int n0 = (idx & 1) * 64;
    f32x4 acc[4];
    const f32x4 z = {0.f, 0.f, 0.f, 0.f};
    acc[0] = z; acc[1] = z; acc[2] = z; acc[3] = z;
    const float* arow = ea + (size_t)(m0 + r16) * EDIM + quad * 8;
    #pragma unroll
    for (int kk = 0; kk < 2; ++kk) {
      float4 a0 = *(const float4*)(arow + kk * 32);
      float4 a1 = *(const float4*)(arow + kk * 32 + 4);
      u16x8 au;
      au[0] = f2bf(a0.x); au[1] = f2bf(a0.y); au[2] = f2bf(a0.z); au[3] = f2bf(a0.w);
      au[4] = f2bf(a1.x); au[5] = f2bf(a1.y); au[6] = f2bf(a1.z); au[7] = f2bf(a1.w);
      bf16x8 av = __builtin_bit_cast(bf16x8, au);
      #pragma unroll
      for (int s = 0; s < 4; ++s) {
        u16x8 bu = *(const u16x8*)(CWE + (size_t)(n0 + s * 16 + r16) * EDIM + kk * 32 + quad * 8);
        acc[s] = __builtin_amdgcn_mfma_f32_16x16x32_bf16(
            av, __builtin_bit_cast(bf16x8, bu), acc[s], 0, 0, 0);
      }
    }
    #pragma unroll
    for (int s = 0; s < 4; ++s) {
      int j = n0 + s * 16 + r16;
      float bias = bk[j];
      #pragma unroll
      for (int r = 0; r < 4; ++r) {
        int m = m0 + quad * 4 + r;
        WeKb[(size_t)m * DIM + j] = f2bf(acc[s][r] + bias);
      }
    }
  }
}

// r6 attention body: one wave, one node, per-wave LDS region abuf.
static __device__ __forceinline__ void attn_node(
    int n, unsigned char* __restrict__ abuf, int lane,
    const unsigned short* __restrict__ qb, const unsigned short* __restrict__ Kb,
    const unsigned short* __restrict__ Vb, const unsigned short* __restrict__ WeKb,
    const int* __restrict__ nedges, const int* __restrict__ enodes,
    unsigned short* __restrict__ ctxb)
{
  float* ldsP = (float*)(abuf + AOFF_P);
  const int l = lane & 31, half = lane >> 5;
  const int h = lane >> 3;
  const int c0 = lane * 2;

  int4 e4 = *(const int4*)(nedges + (size_t)n * DEG);
  int4 m0i = *(const int4*)(enodes + (size_t)e4.x * KPE);
  int4 m1i = *(const int4*)(enodes + (size_t)e4.x * KPE + 4);
  int4 m2i = *(const int4*)(enodes + (size_t)e4.y * KPE);
  int4 m3i = *(const int4*)(enodes + (size_t)e4.y * KPE + 4);
  int4 m4i = *(const int4*)(enodes + (size_t)e4.z * KPE);
  int4 m5i = *(const int4*)(enodes + (size_t)e4.z * KPE + 4);
  int4 m6i = *(const int4*)(enodes + (size_t)e4.w * KPE);
  int4 m7i = *(const int4*)(enodes + (size_t)e4.w * KPE + 4);

#define STAGE(off, table, row) GLDS((const u32*)((table) + (size_t)(row) * DIM) + lane, abuf + (off), 4)
  STAGE(AOFF_K + 0  * 272, Kb, m0i.x); STAGE(AOFF_K + 1  * 272, Kb, m0i.y);
  STAGE(AOFF_K + 2  * 272, Kb, m0i.z); STAGE(AOFF_K + 3  * 272, Kb, m0i.w);
  STAGE(AOFF_K + 4  * 272, Kb, m1i.x); STAGE(AOFF_K + 5  * 272, Kb, m1i.y);
  STAGE(AOFF_K + 6  * 272, Kb, m1i.z); STAGE(AOFF_K + 7  * 272, Kb, m1i.w);
  STAGE(AOFF_K + 8  * 272, Kb, m2i.x); STAGE(AOFF_K + 9  * 272, Kb, m2i.y);
  STAGE(AOFF_K + 10 * 272, Kb, m2i.z); STAGE(AOFF_K + 11 * 272, Kb, m2i.w);
  STAGE(AOFF_K + 12 * 272, Kb, m3i.x); STAGE(AOFF_K + 13 * 272, Kb, m3i.y);
  STAGE(AOFF_K + 14 * 272, Kb, m3i.z); STAGE(AOFF_K + 15 * 272, Kb, m3i.w);
  STAGE(AOFF_K + 16 * 272, Kb, m4i.x); STAGE(AOFF_K + 17 * 272, Kb, m4i.y);
  STAGE(AOFF_K + 18 * 272, Kb, m4i.z); STAGE(AOFF_K + 19 * 272, Kb, m4i.w);
  STAGE(AOFF_K + 20 * 272, Kb, m5i.x); STAGE(AOFF_K + 21 * 272, Kb, m5i.y);
  STAGE(AOFF_K + 22 * 272, Kb, m5i.z); STAGE(AOFF_K + 23 * 272, Kb, m5i.w);
  STAGE(AOFF_K + 24 * 272, Kb, m6i.x); STAGE(AOFF_K + 25 * 272, Kb, m6i.y);
  STAGE(AOFF_K + 26 * 272, Kb, m6i.z); STAGE(AOFF_K + 27 * 272, Kb, m6i.w);
  STAGE(AOFF_K + 28 * 272, Kb, m7i.x); STAGE(AOFF_K + 29 * 272, Kb, m7i.y);
  STAGE(AOFF_K + 30 * 272, Kb, m7i.z); STAGE(AOFF_K + 31 * 272, Kb, m7i.w);
  STAGE(AOFF_E + 0 * 272, WeKb, e4.x); STAGE(AOFF_E + 1 * 272, WeKb, e4.y);
  STAGE(AOFF_E + 2 * 272, WeKb, e4.z); STAGE(AOFF_E + 3 * 272, WeKb, e4.w);
#undef STAGE

  const u32x4* qp = (const u32x4*)(qb + (size_t)n * DIM + half * 64);
  u32x4 qv[8];
  #pragma unroll
  for (int ch = 0; ch < 8; ++ch) qv[ch] = __builtin_nontemporal_load(qp + ch);

  asm volatile("" ::: "memory");

  u32 vv[32];
#define VLOAD(t, row) vv[t] = *(const u32*)(Vb + (size_t)(row) * DIM + c0)
  VLOAD(0,  m0i.x); VLOAD(1,  m0i.y); VLOAD(2,  m0i.z); VLOAD(3,  m0i.w);
  VLOAD(4,  m1i.x); VLOAD(5,  m1i.y); VLOAD(6,  m1i.z); VLOAD(7,  m1i.w);
  VLOAD(8,  m2i.x); VLOAD(9,  m2i.y); VLOAD(10, m2i.z); VLOAD(11, m2i.w);
  VLOAD(12, m3i.x); VLOAD(13, m3i.y); VLOAD(14, m3i.z); VLOAD(15, m3i.w);
  VLOAD(16, m4i.x); VLOAD(17, m4i.y); VLOAD(18, m4i.z); VLOAD(19, m4i.w);
  VLOAD(20, m5i.x); VLOAD(21, m5i.y); VLOAD(22, m5i.z); VLOAD(23, m5i.w);
  VLOAD(24, m6i.x); VLOAD(25, m6i.y); VLOAD(26, m6i.z); VLOAD(27, m6i.w);
  VLOAD(28, m7i.x); VLOAD(29, m7i.y); VLOAD(30, m7i.z); VLOAD(31, m7i.w);
#undef VLOAD

  asm volatile("s_waitcnt vmcnt(32)" ::: "memory");

  const unsigned char* krow = abuf + AOFF_K + l * 272 + half * 128;
  const unsigned char* erow = abuf + AOFF_E + (l >> 3) * 272 + half * 128;
  float s[4] = {0.f, 0.f, 0.f, 0.f};
  #pragma unroll
  for (int ch = 0; ch < 8; ++ch) {
    uint4 kc = *(const uint4*)(krow + ch * 16);
    uint4 ec = *(const uint4*)(erow + ch * 16);
    const int hi = ch >> 1;
    float t = s[hi];
    t = dot2bf(qv[ch].x, kc.x, t); t = dot2bf(qv[ch].x, ec.x, t);
    t = dot2bf(qv[ch].y, kc.y, t); t = dot2bf(qv[ch].y, ec.y, t);
    t = dot2bf(qv[ch].z, kc.z, t); t = dot2bf(qv[ch].z, ec.z, t);
    t = dot2bf(qv[ch].w, kc.w, t); t = dot2bf(qv[ch].w, ec.w, t);
    s[hi] = t;
  }

  #pragma unroll
  for (int hi = 0; hi < 4; ++hi) {
    float vmax = s[hi];
    #pragma unroll
    for (int off = 16; off >= 1; off >>= 1)
      vmax = fmaxf(vmax, __shfl_xor(vmax, off, 32));
    float ex = __expf(s[hi] - vmax);
    float sum = ex;
    #pragma unroll
    for (int off = 16; off >= 1; off >>= 1)
      sum += __shfl_xor(sum, off, 32);
    ldsP[(half * 4 + hi) * 36 + l] = ex / sum;
  }

  float a0 = 0.f, a1 = 0.f;
  #pragma unroll
  for (int t = 0; t < 8; ++t) {
    float4 p4 = *(const float4*)(ldsP + h * 36 + t * 4);
    a0 = fmaf(p4.x, bflo(vv[t * 4 + 0]), a0); a1 = fmaf(p4.x, bfhi(vv[t * 4 + 0]), a1);
    a0 = fmaf(p4.y, bflo(vv[t * 4 + 1]), a0); a1 = fmaf(p4.y, bfhi(vv[t * 4 + 1]), a1);
    a0 = fmaf(p4.z, bflo(vv[t * 4 + 2]), a0); a1 = fmaf(p4.z, bfhi(vv[t * 4 + 2]), a1);
    a0 = fmaf(p4.w, bflo(vv[t * 4 + 3]), a0); a1 = fmaf(p4.w, bfhi(vv[t * 4 + 3]), a1);
  }
  unsigned int pk = (unsigned int)f2bf(a0) | ((unsigned int)f2bf(a1) << 16);
  __builtin_nontemporal_store(pk, (u32*)(ctxb + (size_t)n * DIM + c0));
}

// attn: 8192 blocks x 256 threads (4 waves, 1 node/wave). Big-block grid cuts
// the ~2 ns/block dispatch overhead of the 32768-tiny-block variant (r6 vs r7
// residual evidence: 136 -> 71 us). (256,3): LDS 43.8 KB -> 3 blocks/CU, VGPR
// cap ~170 >= measured 128 -> 12 waves/CU (r6 had ~11).
__global__ __launch_bounds__(256, 3) void attn_kernel(
    const unsigned short* __restrict__ qb, const unsigned short* __restrict__ Kb,
    const unsigned short* __restrict__ Vb, const unsigned short* __restrict__ WeKb,
    const int* __restrict__ nedges, const int* __restrict__ enodes,
    unsigned short* __restrict__ ctxb)
{
  __shared__ __align__(16) unsigned char slds[AWAVESZ * 4];
  const int wave = threadIdx.x >> 6, lane = threadIdx.x & 63;
  attn_node(blockIdx.x * 4 + wave, slds + wave * AWAVESZ, lane,
            qb, Kb, Vb, WeKb, nedges, enodes, ctxb);
}

// ---------------- g4: ctx @ Wo^T + bo, ReLU -> out fp32 ----------------
__global__ __launch_bounds__(256) void g4_kernel(
    const unsigned short* __restrict__ ctxb, const unsigned short* __restrict__ Wob,
    const float* __restrict__ bo, float* __restrict__ out)
{
  const int wave = threadIdx.x >> 6, lane = threadIdx.x & 63;
  const int r16 = lane & 15, quad = lane >> 4;
  const int bx = blockIdx.x & 511, by = blockIdx.x >> 9;
  const int m0 = bx * 64 + wave * 16;
  const int n0 = by * 64;
  f32x4 acc[4];
  const f32x4 z = {0.f, 0.f, 0.f, 0.f};
  acc[0] = z; acc[1] = z; acc[2] = z; acc[3] = z;
  #pragma unroll
  for (int kk = 0; kk < 4; ++kk) {
    u16x8 au = *(const u16x8*)(ctxb + (size_t)(m0 + r16) * DIM + kk * 32 + quad * 8);
    bf16x8 av = __builtin_bit_cast(bf16x8, au);
    #pragma unroll
    for (int s = 0; s < 4; ++s) {
      u16x8 bu = *(const u16x8*)(Wob + (size_t)(n0 + s * 16 + r16) * DIM + kk * 32 + quad * 8);
      acc[s] = __builtin_amdgcn_mfma_f32_16x16x32_bf16(
          av, __builtin_bit_cast(bf16x8, bu), acc[s], 0, 0, 0);
    }
  }
  #pragma unroll
  for (int s = 0; s < 4; ++s) {
    int j = n0 + s * 16 + r16;
    float bias = bo[j];
    #pragma unroll
    for (int r = 0; r < 4; ++r) {
      int m = m0 + quad * 4 + r;
      float v = acc[s][r] + bias;
      out[(size_t)m * DIM + j] = v > 0.f ? v : 0.f;
    }
  }
}

extern "C" void kernel_launch(void* const* d_in, const int* in_sizes, int n_in,
                              void* d_out, int out_size, void* d_ws, size_t ws_size,
                              hipStream_t stream)
{
  const float* x     = (const float*)d_in[0];
  const float* ea    = (const float*)d_in[1];
  const int* nedges  = (const int*)d_in[2];
  const int* enodes  = (const int*)d_in[3];
  const float* Wlin  = (const float*)d_in[4];
  const float* Wedge = (const float*)d_in[5];
  const float* Wq    = (const float*)d_in[6];
  const float* Wk    = (const float*)d_in[7];
  const float* Wv    = (const float*)d_in[8];
  const float* bq    = (const float*)d_in[9];
  const float* bk    = (const float*)d_in[10];
  const float* bv    = (const float*)d_in[11];
  const float* Wo    = (const float*)d_in[12];
  const float* bo    = (const float*)d_in[13];
  float* out = (float*)d_out;

  unsigned short* wsp = (unsigned short*)d_ws;
  unsigned short* CW   = wsp;  wsp += 384 * 128;
  unsigned short* CWE  = wsp;  wsp += 128 * 64;
  unsigned short* Wob  = wsp;  wsp += 128 * 128;
  unsigned short* qb   = wsp;  wsp += (size_t)N_NODES * DIM;
  unsigned short* Kb   = wsp;  wsp += (size_t)N_NODES * DIM;
  unsigned short* Vb   = wsp;  wsp += (size_t)N_NODES * DIM;
  unsigned short* WeKb = wsp;  wsp += (size_t)N_EDGES * DIM;
  unsigned short* ctxb = wsp;  wsp += (size_t)N_NODES * DIM;

  wprep_kernel<<<dim3(288), dim3(256), 0, stream>>>(Wq, Wk, Wv, Wlin, Wedge, Wo, CW, CWE, Wob);
  g12_kernel<<<dim3(1024), dim3(256), 0, stream>>>(x, CW, bq, bv, qb, Kb, Vb, ea, CWE, bk, WeKb);
  attn_kernel<<<dim3(8192), dim3(256), 0, stream>>>(qb, Kb, Vb, WeKb, nedges, enodes, ctxb);
  g4_kernel<<<dim3(1024), dim3(256), 0, stream>>>(ctxb, Wob, bo, out);
}